// Round 1
// baseline (81.406 us; speedup 1.0000x reference)
//
#include <hip/hip_runtime.h>
#include <math.h>

// SoAGREE fused forward: one block per batch element b.
// B=1024, M=16, F=32, D=64. All fp32.
// Block = 256 threads = 4 waves; wave w handles members m = it*4+w, it=0..3.

__global__ __launch_bounds__(256) void soagree_kernel(
    const int* __restrict__ group_inputs,   // [B]
    const int* __restrict__ item_inputs,    // [B]
    const int* __restrict__ member_ids,     // [B,16]
    const int* __restrict__ follow_ids,     // [B,16,32]
    const float* __restrict__ user_table,   // [NU,64]
    const float* __restrict__ item_table,   // [NI,64]
    const float* __restrict__ group_table,  // [NG,64]
    const float* __restrict__ follow_table, // [NU,64]
    const float* __restrict__ fatt_w1, const float* __restrict__ fatt_b1,
    const float* __restrict__ fatt_w2, const float* __restrict__ fatt_b2,
    const float* __restrict__ att_w1,  const float* __restrict__ att_b1,
    const float* __restrict__ att_w2,  const float* __restrict__ att_b2,
    const float* __restrict__ pred_w1, const float* __restrict__ pred_b1,
    const float* __restrict__ pred_w2, const float* __restrict__ pred_b2,
    float* __restrict__ out)               // [B]
{
    const int b    = blockIdx.x;
    const int tid  = threadIdx.x;
    const int w    = tid >> 6;    // wave id 0..3
    const int lane = tid & 63;

    __shared__ float s_w1f[128 * 16];      // fatt_w1 staged
    __shared__ float s_w1a[128 * 16];      // att_w1 staged
    __shared__ float s_femb[4][32][65];    // per-wave follow-emb tile (padded)
    __shared__ float s_uemb[16][65];       // member user embeddings (padded)
    __shared__ float s_mem[16][65];        // aggregated member vectors (padded)
    __shared__ float s_iemb[64];
    __shared__ float s_gemb[64];
    __shared__ float s_upart[16][16];      // per-member u @ w1[64:] + b1
    __shared__ float s_ipart[16];          // i @ att_w1[64:] + att_b1
    __shared__ float s_fw[4][32];          // per-wave follow softmax weights
    __shared__ float s_scores[16];
    __shared__ float s_mw[16];
    __shared__ float s_gfin[64];

    // ---- phase 0: stage weights + embeddings ----
    for (int i = tid; i < 128 * 16; i += 256) {
        s_w1f[i] = fatt_w1[i];
        s_w1a[i] = att_w1[i];
    }
    if (tid < 64) {
        s_iemb[tid] = item_table[(size_t)item_inputs[b] * 64 + tid];
    } else if (tid < 128) {
        s_gemb[tid - 64] = group_table[(size_t)group_inputs[b] * 64 + (tid - 64)];
    }
    for (int m = w; m < 16; m += 4) {
        int uid = member_ids[b * 16 + m];
        s_uemb[m][lane] = user_table[(size_t)uid * 64 + lane];
    }
    __syncthreads();

    // ---- phase 0.5: u_part[m][j] and i_part[j] (shared halves of the MLPs) ----
    {
        int m = tid >> 4, j = tid & 15;
        float acc = fatt_b1[j];
        #pragma unroll
        for (int d = 0; d < 64; ++d)
            acc += s_uemb[m][d] * s_w1f[(64 + d) * 16 + j];
        s_upart[m][j] = acc;
    }
    if (tid < 16) {
        float a2 = att_b1[tid];
        #pragma unroll
        for (int d = 0; d < 64; ++d)
            a2 += s_iemb[d] * s_w1a[(64 + d) * 16 + tid];
        s_ipart[tid] = a2;
    }
    __syncthreads();

    // ---- phase 1: follow-level attention, one member per wave per iter ----
    for (int it = 0; it < 4; ++it) {
        const int m = it * 4 + w;
        const int fbase = (b * 16 + m) * 32;

        // gather 32 follow rows (coalesced 256B each) into LDS
        #pragma unroll
        for (int f = 0; f < 32; ++f) {
            int fid = follow_ids[fbase + f];
            s_femb[w][f][lane] = follow_table[(size_t)fid * 64 + lane];
        }
        __syncthreads();

        // scores: lane f<32 computes h = relu(f_emb@w1a + u_part), s = h@w2 + b2
        float fwv = 0.f;
        if (lane < 32) {
            const int f = lane;
            float h[16];
            #pragma unroll
            for (int j = 0; j < 16; ++j) h[j] = s_upart[m][j];
            #pragma unroll 8
            for (int d = 0; d < 64; ++d) {
                float v = s_femb[w][f][d];
                #pragma unroll
                for (int j = 0; j < 16; ++j)
                    h[j] += v * s_w1f[d * 16 + j];
            }
            float s = fatt_b2[0];
            #pragma unroll
            for (int j = 0; j < 16; ++j)
                s += fmaxf(h[j], 0.f) * fatt_w2[j];
            fwv = s;
        }
        // softmax over the 32-lane group (masks <=16 stay within each half-wave)
        float mx = fwv;
        #pragma unroll
        for (int mask = 16; mask >= 1; mask >>= 1)
            mx = fmaxf(mx, __shfl_xor(mx, mask));
        float e = expf(fwv - mx);
        float sm = e;
        #pragma unroll
        for (int mask = 16; mask >= 1; mask >>= 1)
            sm += __shfl_xor(sm, mask);
        if (lane < 32) s_fw[w][lane] = e / sm;
        __syncthreads();

        // members[m][d] = sum_f fw[f]*femb[f][d] + u_emb[d]   (all 64 lanes, d=lane)
        float acc = s_uemb[m][lane];
        #pragma unroll
        for (int f = 0; f < 32; ++f)
            acc += s_fw[w][f] * s_femb[w][f][lane];
        s_mem[m][lane] = acc;
        __syncthreads();
    }

    // ---- phase 2: member-level attention conditioned on item ----
    {
        int m = tid >> 4, j = tid & 15;
        float acc = s_ipart[j];
        #pragma unroll
        for (int d = 0; d < 64; ++d)
            acc += s_mem[m][d] * s_w1a[d * 16 + j];
        float contrib = fmaxf(acc, 0.f) * att_w2[j];
        #pragma unroll
        for (int mask = 8; mask >= 1; mask >>= 1)
            contrib += __shfl_xor(contrib, mask);
        if (j == 0) s_scores[m] = contrib + att_b2[0];
    }
    __syncthreads();
    if (tid < 16) {
        float s = s_scores[tid];
        float mx2 = s;
        #pragma unroll
        for (int mask = 8; mask >= 1; mask >>= 1)
            mx2 = fmaxf(mx2, __shfl_xor(mx2, mask));
        float e2 = expf(s - mx2);
        float sm2 = e2;
        #pragma unroll
        for (int mask = 8; mask >= 1; mask >>= 1)
            sm2 += __shfl_xor(sm2, mask);
        s_mw[tid] = e2 / sm2;
    }
    __syncthreads();
    if (tid < 64) {
        float g = s_gemb[tid];
        #pragma unroll
        for (int mm = 0; mm < 16; ++mm)
            g += s_mw[mm] * s_mem[mm][tid];
        s_gfin[tid] = g;
    }
    __syncthreads();

    // ---- phase 3: NCF predict head ----
    if (tid < 8) {
        const int j = tid;
        float acc = pred_b1[j];
        #pragma unroll 16
        for (int k = 0; k < 64; ++k) {
            float g = s_gfin[k], ie = s_iemb[k];
            acc += (g * ie) * pred_w1[k * 8 + j];
            acc += g  * pred_w1[(64 + k) * 8 + j];
            acc += ie * pred_w1[(128 + k) * 8 + j];
        }
        float contrib = fmaxf(acc, 0.f) * pred_w2[j];
        #pragma unroll
        for (int mask = 4; mask >= 1; mask >>= 1)
            contrib += __shfl_xor(contrib, mask);
        if (j == 0) {
            float z = contrib + pred_b2[0];
            out[b] = 1.f / (1.f + expf(-z));
        }
    }
}

extern "C" void kernel_launch(void* const* d_in, const int* in_sizes, int n_in,
                              void* d_out, int out_size, void* d_ws, size_t ws_size,
                              hipStream_t stream) {
    const int*   group_inputs = (const int*)d_in[0];
    const int*   item_inputs  = (const int*)d_in[1];
    const int*   member_ids   = (const int*)d_in[2];
    const int*   follow_ids   = (const int*)d_in[3];
    const float* user_table   = (const float*)d_in[4];
    const float* item_table   = (const float*)d_in[5];
    const float* group_table  = (const float*)d_in[6];
    const float* follow_table = (const float*)d_in[7];
    const float* fatt_w1 = (const float*)d_in[8];
    const float* fatt_b1 = (const float*)d_in[9];
    const float* fatt_w2 = (const float*)d_in[10];
    const float* fatt_b2 = (const float*)d_in[11];
    const float* att_w1  = (const float*)d_in[12];
    const float* att_b1  = (const float*)d_in[13];
    const float* att_w2  = (const float*)d_in[14];
    const float* att_b2  = (const float*)d_in[15];
    const float* pred_w1 = (const float*)d_in[16];
    const float* pred_b1 = (const float*)d_in[17];
    const float* pred_w2 = (const float*)d_in[18];
    const float* pred_b2 = (const float*)d_in[19];
    float* outp = (float*)d_out;

    const int B = in_sizes[0];   // 1024

    soagree_kernel<<<B, 256, 0, stream>>>(
        group_inputs, item_inputs, member_ids, follow_ids,
        user_table, item_table, group_table, follow_table,
        fatt_w1, fatt_b1, fatt_w2, fatt_b2,
        att_w1, att_b1, att_w2, att_b2,
        pred_w1, pred_b1, pred_w2, pred_b2,
        outp);
}

// Round 2
// 70.362 us; speedup vs baseline: 1.1570x; 1.1570x over previous
//
#include <hip/hip_runtime.h>
#include <math.h>

// SoAGREE fused forward. One block (256 thr = 4 waves) per batch element.
// B=1024, M=16, F=32, D=64, fp32.
// Phase 1: wave w owns member m = it*4+w (it=0..3), fully wave-local:
//   gather 32 follow rows -> regs (lane=(f,h) holds row f, d-half h, 32 floats)
//   -> swizzled LDS write (for the weighted sum) -> score MLP from regs
//   -> 32-lane softmax -> weighted sum from LDS. No block barriers inside.

__global__ __launch_bounds__(256, 3) void soagree_kernel(
    const int* __restrict__ group_inputs,   // [B]
    const int* __restrict__ item_inputs,    // [B]
    const int* __restrict__ member_ids,     // [B,16]
    const int* __restrict__ follow_ids,     // [B,16,32]
    const float* __restrict__ user_table,   // [NU,64]
    const float* __restrict__ item_table,   // [NI,64]
    const float* __restrict__ group_table,  // [NG,64]
    const float* __restrict__ follow_table, // [NU,64]
    const float* __restrict__ fatt_w1, const float* __restrict__ fatt_b1,
    const float* __restrict__ fatt_w2, const float* __restrict__ fatt_b2,
    const float* __restrict__ att_w1,  const float* __restrict__ att_b1,
    const float* __restrict__ att_w2,  const float* __restrict__ att_b2,
    const float* __restrict__ pred_w1, const float* __restrict__ pred_b1,
    const float* __restrict__ pred_w2, const float* __restrict__ pred_b2,
    float* __restrict__ out)               // [B]
{
    const int b    = blockIdx.x;
    const int tid  = threadIdx.x;
    const int w    = tid >> 6;    // wave id 0..3
    const int lane = tid & 63;
    const int f    = lane & 31;   // follow row owned in score phase
    const int h    = lane >> 5;   // d-half (0: d<32, 1: d>=32)

    __shared__ float s_w1[128 * 16];      // fatt_w1 in phase 0/1, att_w1 in phase 2
    __shared__ float s_femb[4][32][64];   // per-wave follow tile, XOR-swizzled cols
    __shared__ float s_uemb[16][65];      // member user embeddings (padded)
    __shared__ float s_mem[16][65];       // aggregated member vectors (padded)
    __shared__ float s_upart[16][16];     // u @ fatt_w1[64:] + fatt_b1
    __shared__ float s_ipart[16];         // i @ att_w1[64:] + att_b1
    __shared__ float s_iemb[64];
    __shared__ float s_gemb[64];
    __shared__ float s_gfin[64];
    __shared__ float s_scores[16];
    __shared__ float s_mw[16];
    __shared__ float s_fw2[16];           // fatt_w2

    // ---- phase 0: stage weights + embeddings ----
    for (int i = tid; i < 2048; i += 256) s_w1[i] = fatt_w1[i];
    if (tid < 16) s_fw2[tid] = fatt_w2[tid];
    if (tid < 64) {
        s_iemb[tid] = item_table[(size_t)item_inputs[b] * 64 + tid];
    } else if (tid < 128) {
        s_gemb[tid - 64] = group_table[(size_t)group_inputs[b] * 64 + (tid - 64)];
    }
    for (int m = w; m < 16; m += 4) {
        int uid = member_ids[b * 16 + m];
        s_uemb[m][lane] = user_table[(size_t)uid * 64 + lane];
    }
    __syncthreads();

    // ---- phase 0.5: u_part[m][j], i_part[j] (shared halves of the MLPs) ----
    {
        int m = tid >> 4, j = tid & 15;
        float acc = fatt_b1[j];
        #pragma unroll
        for (int d = 0; d < 64; ++d)
            acc += s_uemb[m][d] * s_w1[(64 + d) * 16 + j];
        s_upart[m][j] = acc;
    }
    if (tid < 16) {
        float a2 = att_b1[tid];
        #pragma unroll
        for (int d = 0; d < 64; ++d)
            a2 += s_iemb[d] * att_w1[(64 + d) * 16 + tid];  // global, coalesced, L2-hot
        s_ipart[tid] = a2;
    }
    __syncthreads();

    const float fb2 = fatt_b2[0];

    // ---- phase 1: follow attention, one member per wave per iter, no block syncs ----
    for (int it = 0; it < 4; ++it) {
        const int m = it * 4 + w;

        // gather: lane (f,h) loads row f, cols [h*32, h*32+32) as 8 float4
        const int fid = follow_ids[(b * 16 + m) * 32 + f];
        const float* src = follow_table + (size_t)fid * 64 + (h << 5);
        float4 r[8];
        #pragma unroll
        for (int q = 0; q < 8; ++q) r[q] = ((const float4*)src)[q];

        // swizzled LDS write: element d of row f -> col (d ^ ((f&7)<<2))
        const int swz = (lane & 7) << 2;
        #pragma unroll
        for (int q = 0; q < 8; ++q)
            *(float4*)&s_femb[w][f][(((h << 5) | (q << 2)) ^ swz)] = r[q];

        // score MLP from registers; w1 from LDS (2-addr broadcast reads)
        float hacc[16];
        #pragma unroll
        for (int j = 0; j < 16; ++j) hacc[j] = h ? 0.f : s_upart[m][j];
        #pragma unroll
        for (int q = 0; q < 8; ++q) {
            #pragma unroll
            for (int t = 0; t < 4; ++t) {
                const int d = (h << 5) + (q << 2) + t;
                const float v = ((const float*)&r[q])[t];
                #pragma unroll
                for (int jj = 0; jj < 4; ++jj) {
                    float4 wv = *(const float4*)&s_w1[d * 16 + (jj << 2)];
                    hacc[jj * 4 + 0] += v * wv.x;
                    hacc[jj * 4 + 1] += v * wv.y;
                    hacc[jj * 4 + 2] += v * wv.z;
                    hacc[jj * 4 + 3] += v * wv.w;
                }
            }
        }
        // combine the two d-halves, relu, dot with w2
        float sc = fb2;
        #pragma unroll
        for (int j = 0; j < 16; ++j) {
            float hj = hacc[j] + __shfl_xor(hacc[j], 32);
            sc += fmaxf(hj, 0.f) * s_fw2[j];
        }
        // softmax over the 32 f-lanes (both halves hold identical values)
        float mx = sc;
        #pragma unroll
        for (int mk = 16; mk >= 1; mk >>= 1) mx = fmaxf(mx, __shfl_xor(mx, mk));
        const float e = __expf(sc - mx);
        float se = e;
        #pragma unroll
        for (int mk = 16; mk >= 1; mk >>= 1) se += __shfl_xor(se, mk);
        const float fwv = e / se;

        // make this wave's LDS writes visible before the cross-lane reads
        asm volatile("s_waitcnt lgkmcnt(0)" ::: "memory");
        __builtin_amdgcn_sched_barrier(0);

        // weighted sum: lane = d, loop rows; swizzled read is conflict-free
        float acc = s_uemb[m][lane];
        #pragma unroll
        for (int ff = 0; ff < 32; ++ff) {
            const float wgt = __shfl(fwv, ff);
            acc += wgt * s_femb[w][ff][lane ^ ((ff & 7) << 2)];
        }
        s_mem[m][lane] = acc;
    }
    __syncthreads();

    // ---- phase 2: member attention (reuse s_w1 for att_w1) ----
    for (int i = tid; i < 2048; i += 256) s_w1[i] = att_w1[i];
    __syncthreads();
    {
        int m = tid >> 4, j = tid & 15;
        float acc = s_ipart[j];
        #pragma unroll
        for (int d = 0; d < 64; ++d)
            acc += s_mem[m][d] * s_w1[d * 16 + j];
        float contrib = fmaxf(acc, 0.f) * att_w2[j];
        #pragma unroll
        for (int mk = 8; mk >= 1; mk >>= 1) contrib += __shfl_xor(contrib, mk);
        if (j == 0) s_scores[m] = contrib + att_b2[0];
    }
    __syncthreads();
    if (tid < 16) {
        float s = s_scores[tid];
        float mx2 = s;
        #pragma unroll
        for (int mk = 8; mk >= 1; mk >>= 1) mx2 = fmaxf(mx2, __shfl_xor(mx2, mk));
        float e2 = __expf(s - mx2);
        float sm2 = e2;
        #pragma unroll
        for (int mk = 8; mk >= 1; mk >>= 1) sm2 += __shfl_xor(sm2, mk);
        s_mw[tid] = e2 / sm2;
    }
    __syncthreads();
    if (tid < 64) {
        float g = s_gemb[tid];
        #pragma unroll
        for (int mm = 0; mm < 16; ++mm)
            g += s_mw[mm] * s_mem[mm][tid];
        s_gfin[tid] = g;
    }
    __syncthreads();

    // ---- phase 3: NCF predict head ----
    if (tid < 8) {
        const int j = tid;
        float acc = pred_b1[j];
        #pragma unroll 16
        for (int k = 0; k < 64; ++k) {
            float g = s_gfin[k], ie = s_iemb[k];
            acc += (g * ie) * pred_w1[k * 8 + j];
            acc += g  * pred_w1[(64 + k) * 8 + j];
            acc += ie * pred_w1[(128 + k) * 8 + j];
        }
        float contrib = fmaxf(acc, 0.f) * pred_w2[j];
        #pragma unroll
        for (int mk = 4; mk >= 1; mk >>= 1) contrib += __shfl_xor(contrib, mk);
        if (j == 0) {
            float z = contrib + pred_b2[0];
            out[b] = 1.f / (1.f + __expf(-z));
        }
    }
}

extern "C" void kernel_launch(void* const* d_in, const int* in_sizes, int n_in,
                              void* d_out, int out_size, void* d_ws, size_t ws_size,
                              hipStream_t stream) {
    const int*   group_inputs = (const int*)d_in[0];
    const int*   item_inputs  = (const int*)d_in[1];
    const int*   member_ids   = (const int*)d_in[2];
    const int*   follow_ids   = (const int*)d_in[3];
    const float* user_table   = (const float*)d_in[4];
    const float* item_table   = (const float*)d_in[5];
    const float* group_table  = (const float*)d_in[6];
    const float* follow_table = (const float*)d_in[7];
    const float* fatt_w1 = (const float*)d_in[8];
    const float* fatt_b1 = (const float*)d_in[9];
    const float* fatt_w2 = (const float*)d_in[10];
    const float* fatt_b2 = (const float*)d_in[11];
    const float* att_w1  = (const float*)d_in[12];
    const float* att_b1  = (const float*)d_in[13];
    const float* att_w2  = (const float*)d_in[14];
    const float* att_b2  = (const float*)d_in[15];
    const float* pred_w1 = (const float*)d_in[16];
    const float* pred_b1 = (const float*)d_in[17];
    const float* pred_w2 = (const float*)d_in[18];
    const float* pred_b2 = (const float*)d_in[19];
    float* outp = (float*)d_out;

    const int B = in_sizes[0];   // 1024

    soagree_kernel<<<B, 256, 0, stream>>>(
        group_inputs, item_inputs, member_ids, follow_ids,
        user_table, item_table, group_table, follow_table,
        fatt_w1, fatt_b1, fatt_w2, fatt_b2,
        att_w1, att_b1, att_w2, att_b2,
        pred_w1, pred_b1, pred_w2, pred_b2,
        outp);
}

// Round 3
// 52.902 us; speedup vs baseline: 1.5388x; 1.3300x over previous
//
#include <hip/hip_runtime.h>
#include <math.h>

// SoAGREE fused forward. One block (256 thr = 4 waves) per batch element.
// B=1024, M=16, F=32, D=64, fp32.
// Phase 1: wave w processes member PAIRS (w*4+2pr, w*4+2pr+1), pr=0,1.
//   lane = (f = lane&31, mh = lane>>5): member m = pairbase + mh, row f.
//   Each lane gathers its FULL 256B follow row into 16 float4 regs.
//   Score MLP: d is wave-uniform -> fatt_w1 rows come in as s_load (SGPR),
//   FMAs use the scalar operand -> zero LDS traffic for weights.
//   Weighted sum: scaled rows -> small per-wave half-d LDS tile -> column reads.

#define TROW 36                 // padded row stride (floats) in the transpose tile
#define TMH  (32 * TROW + 16)   // mh-section stride; +16 floats = 64B bank offset

__global__ __launch_bounds__(256, 3) void soagree_kernel(
    const int* __restrict__ group_inputs,   // [B]
    const int* __restrict__ item_inputs,    // [B]
    const int* __restrict__ member_ids,     // [B,16]
    const int* __restrict__ follow_ids,     // [B,16,32]
    const float* __restrict__ user_table,   // [NU,64]
    const float* __restrict__ item_table,   // [NI,64]
    const float* __restrict__ group_table,  // [NG,64]
    const float* __restrict__ follow_table, // [NU,64]
    const float* __restrict__ fatt_w1, const float* __restrict__ fatt_b1,
    const float* __restrict__ fatt_w2, const float* __restrict__ fatt_b2,
    const float* __restrict__ att_w1,  const float* __restrict__ att_b1,
    const float* __restrict__ att_w2,  const float* __restrict__ att_b2,
    const float* __restrict__ pred_w1, const float* __restrict__ pred_b1,
    const float* __restrict__ pred_w2, const float* __restrict__ pred_b2,
    float* __restrict__ out)               // [B]
{
    const int b    = blockIdx.x;
    const int tid  = threadIdx.x;
    const int w    = tid >> 6;    // wave id 0..3
    const int lane = tid & 63;
    const int f    = lane & 31;   // follow row / d-index within half
    const int mh   = lane >> 5;   // which member of the pair

    __shared__ float s_tile[4][2 * TMH];  // per-wave transpose tile (half-d)
    __shared__ float s_uemb[16][65];      // member user embeddings (padded)
    __shared__ float s_mem[16][65];       // aggregated member vectors (padded)
    __shared__ float s_upart[16][16];     // u @ fatt_w1[64:] + fatt_b1
    __shared__ float s_ipart[16];         // i @ att_w1[64:] + att_b1
    __shared__ float s_iemb[64];
    __shared__ float s_gemb[64];
    __shared__ float s_gfin[64];
    __shared__ float s_scores[16];
    __shared__ float s_mw[16];

    // ---- phase 0: stage embeddings (no weight staging needed anymore) ----
    if (tid < 64) {
        s_iemb[tid] = item_table[(size_t)item_inputs[b] * 64 + tid];
    } else if (tid < 128) {
        s_gemb[tid - 64] = group_table[(size_t)group_inputs[b] * 64 + (tid - 64)];
    }
    for (int m = w; m < 16; m += 4) {
        int uid = member_ids[b * 16 + m];
        s_uemb[m][lane] = user_table[(size_t)uid * 64 + lane];
    }
    __syncthreads();

    // ---- phase 0.5: u_part[m][j], i_part[j] (w1 hi-halves from global, L1-hot) ----
    {
        int m = tid >> 4, j = tid & 15;
        float acc = fatt_b1[j];
        #pragma unroll
        for (int d = 0; d < 64; ++d)
            acc += s_uemb[m][d] * fatt_w1[(64 + d) * 16 + j];
        s_upart[m][j] = acc;
    }
    if (tid < 16) {
        float a2 = att_b1[tid];
        #pragma unroll
        for (int d = 0; d < 64; ++d)
            a2 += s_iemb[d] * att_w1[(64 + d) * 16 + tid];
        s_ipart[tid] = a2;
    }
    __syncthreads();

    float* const tw_base = &s_tile[w][0];

    // ---- phase 1: follow attention, 2 member-pairs per wave, wave-local ----
    #pragma unroll
    for (int pr = 0; pr < 2; ++pr) {
        const int pb = w * 4 + pr * 2;   // pair's first member
        const int m  = pb + mh;          // this lane's member

        // gather: one coalesced id load, then full 256B row -> 16 float4 regs
        const int fid = follow_ids[b * 512 + pb * 32 + lane];
        const float4* src = (const float4*)(follow_table + (size_t)fid * 64);
        float4 r[16];
        #pragma unroll
        for (int q = 0; q < 16; ++q) r[q] = src[q];

        // hacc init from s_upart (2-addr broadcast b128 reads)
        float hacc[16];
        #pragma unroll
        for (int jj = 0; jj < 4; ++jj) {
            float4 up = *(const float4*)&s_upart[m][jj * 4];
            hacc[jj * 4 + 0] = up.x; hacc[jj * 4 + 1] = up.y;
            hacc[jj * 4 + 2] = up.z; hacc[jj * 4 + 3] = up.w;
        }

        // score MLP: d wave-uniform -> fatt_w1[d*16+j] is a scalar (s_load) operand
        const float* rf = (const float*)r;
        #pragma unroll
        for (int d = 0; d < 64; ++d) {
            const float v = rf[d];
            #pragma unroll
            for (int j = 0; j < 16; ++j)
                hacc[j] += v * fatt_w1[d * 16 + j];
        }
        float sc = fatt_b2[0];
        #pragma unroll
        for (int j = 0; j < 16; ++j)
            sc += fmaxf(hacc[j], 0.f) * fatt_w2[j];

        // softmax over the 32 f-lanes of this half (masks <32 stay in-half)
        float mx = sc;
        #pragma unroll
        for (int mk = 16; mk >= 1; mk >>= 1) mx = fmaxf(mx, __shfl_xor(mx, mk));
        const float e = __expf(sc - mx);
        float se = e;
        #pragma unroll
        for (int mk = 16; mk >= 1; mk >>= 1) se += __shfl_xor(se, mk);
        const float fwv = e / se;

        float* const tw = tw_base + mh * TMH + f * TROW;

        // --- d-lo: scaled rows -> tile -> column reduce ---
        #pragma unroll
        for (int q = 0; q < 8; ++q) {
            float4 sr;
            sr.x = r[q].x * fwv; sr.y = r[q].y * fwv;
            sr.z = r[q].z * fwv; sr.w = r[q].w * fwv;
            *(float4*)&tw[q * 4] = sr;
        }
        asm volatile("s_waitcnt lgkmcnt(0)" ::: "memory");
        __builtin_amdgcn_sched_barrier(0);
        {
            float acc = s_uemb[m][f];
            #pragma unroll
            for (int ff = 0; ff < 32; ++ff)
                acc += tw_base[mh * TMH + ff * TROW + f];
            s_mem[m][f] = acc;
        }
        asm volatile("s_waitcnt lgkmcnt(0)" ::: "memory");
        __builtin_amdgcn_sched_barrier(0);

        // --- d-hi: reuse the same tile slots ---
        #pragma unroll
        for (int q = 8; q < 16; ++q) {
            float4 sr;
            sr.x = r[q].x * fwv; sr.y = r[q].y * fwv;
            sr.z = r[q].z * fwv; sr.w = r[q].w * fwv;
            *(float4*)&tw[(q - 8) * 4] = sr;
        }
        asm volatile("s_waitcnt lgkmcnt(0)" ::: "memory");
        __builtin_amdgcn_sched_barrier(0);
        {
            float acc = s_uemb[m][f + 32];
            #pragma unroll
            for (int ff = 0; ff < 32; ++ff)
                acc += tw_base[mh * TMH + ff * TROW + f];
            s_mem[m][f + 32] = acc;
        }
        asm volatile("s_waitcnt lgkmcnt(0)" ::: "memory");
        __builtin_amdgcn_sched_barrier(0);
    }
    __syncthreads();

    // ---- phase 2: member attention (att_w1 lo-half from global, L1-hot) ----
    {
        int m = tid >> 4, j = tid & 15;
        float acc = s_ipart[j];
        #pragma unroll
        for (int d = 0; d < 64; ++d)
            acc += s_mem[m][d] * att_w1[d * 16 + j];
        float contrib = fmaxf(acc, 0.f) * att_w2[j];
        #pragma unroll
        for (int mk = 8; mk >= 1; mk >>= 1) contrib += __shfl_xor(contrib, mk);
        if (j == 0) s_scores[m] = contrib + att_b2[0];
    }
    __syncthreads();
    if (tid < 16) {
        float s = s_scores[tid];
        float mx2 = s;
        #pragma unroll
        for (int mk = 8; mk >= 1; mk >>= 1) mx2 = fmaxf(mx2, __shfl_xor(mx2, mk));
        float e2 = __expf(s - mx2);
        float sm2 = e2;
        #pragma unroll
        for (int mk = 8; mk >= 1; mk >>= 1) sm2 += __shfl_xor(sm2, mk);
        s_mw[tid] = e2 / sm2;
    }
    __syncthreads();
    if (tid < 64) {
        float g = s_gemb[tid];
        #pragma unroll
        for (int mm = 0; mm < 16; ++mm)
            g += s_mw[mm] * s_mem[mm][tid];
        s_gfin[tid] = g;
    }
    __syncthreads();

    // ---- phase 3: NCF predict head ----
    if (tid < 8) {
        const int j = tid;
        float acc = pred_b1[j];
        #pragma unroll 16
        for (int k = 0; k < 64; ++k) {
            float g = s_gfin[k], ie = s_iemb[k];
            acc += (g * ie) * pred_w1[k * 8 + j];
            acc += g  * pred_w1[(64 + k) * 8 + j];
            acc += ie * pred_w1[(128 + k) * 8 + j];
        }
        float contrib = fmaxf(acc, 0.f) * pred_w2[j];
        #pragma unroll
        for (int mk = 4; mk >= 1; mk >>= 1) contrib += __shfl_xor(contrib, mk);
        if (j == 0) {
            float z = contrib + pred_b2[0];
            out[b] = 1.f / (1.f + __expf(-z));
        }
    }
}

extern "C" void kernel_launch(void* const* d_in, const int* in_sizes, int n_in,
                              void* d_out, int out_size, void* d_ws, size_t ws_size,
                              hipStream_t stream) {
    const int*   group_inputs = (const int*)d_in[0];
    const int*   item_inputs  = (const int*)d_in[1];
    const int*   member_ids   = (const int*)d_in[2];
    const int*   follow_ids   = (const int*)d_in[3];
    const float* user_table   = (const float*)d_in[4];
    const float* item_table   = (const float*)d_in[5];
    const float* group_table  = (const float*)d_in[6];
    const float* follow_table = (const float*)d_in[7];
    const float* fatt_w1 = (const float*)d_in[8];
    const float* fatt_b1 = (const float*)d_in[9];
    const float* fatt_w2 = (const float*)d_in[10];
    const float* fatt_b2 = (const float*)d_in[11];
    const float* att_w1  = (const float*)d_in[12];
    const float* att_b1  = (const float*)d_in[13];
    const float* att_w2  = (const float*)d_in[14];
    const float* att_b2  = (const float*)d_in[15];
    const float* pred_w1 = (const float*)d_in[16];
    const float* pred_b1 = (const float*)d_in[17];
    const float* pred_w2 = (const float*)d_in[18];
    const float* pred_b2 = (const float*)d_in[19];
    float* outp = (float*)d_out;

    const int B = in_sizes[0];   // 1024

    soagree_kernel<<<B, 256, 0, stream>>>(
        group_inputs, item_inputs, member_ids, follow_ids,
        user_table, item_table, group_table, follow_table,
        fatt_w1, fatt_b1, fatt_w2, fatt_b2,
        att_w1, att_b1, att_w2, att_b2,
        pred_w1, pred_b1, pred_w2, pred_b2,
        outp);
}